// Round 7
// baseline (128.395 us; speedup 1.0000x reference)
//
#include <hip/hip_runtime.h>
#include <stdint.h>

#define NDIM 8192
#define DDIM 256
#define CAP  256    // candidate capacity — LDS ~2.6 KB
#define MAXK 64
#define RPB  4      // rows per block (software pipeline depth along rows)

typedef float v4f __attribute__((ext_vector_type(4)));

// Map float bits to an unsigned key with the same total order.
__device__ inline uint32_t f2key(float f) {
    uint32_t u = __float_as_uint(f);
    return (u & 0x80000000u) ? ~u : (u | 0x80000000u);
}

__global__ __launch_bounds__(256, 4) void topk_agg_kernel(
    const float* __restrict__ A, const float* __restrict__ X,
    const float* __restrict__ alpha_p, const int* __restrict__ k_p,
    float* __restrict__ out)
{
    const int tid  = threadIdx.x;
    const int lane = tid & 63;
    const int wid  = tid >> 6;
    const int row0 = blockIdx.x * RPB;

    __shared__ unsigned long long cand[CAP];
    __shared__ int s_count;
    __shared__ int s_sel[MAXK];
    __shared__ unsigned long long s_red[4];

    int k = *k_p;
    if (k > MAXK) k = MAXK;           // defensive clamp (k==32 here)
    const float alpha = *alpha_p;

    // Two register row-buffers, ping-ponged across RPB rows. All indexing
    // is compile-time (unrolled) so they stay in VGPRs, never scratch.
    v4f bufA[8], bufB[8];

    // Prime the pipeline: issue row0's loads.
    {
        const v4f* p = reinterpret_cast<const v4f*>(A + (size_t)row0 * NDIM);
        #pragma unroll
        for (int i = 0; i < 8; ++i)
            bufA[i] = __builtin_nontemporal_load(p + i * 256 + tid);
    }

    // Process row (row0+r) whose data is in `cur`; prefetch row (row0+r+1)
    // into `nxt` FIRST so its HBM latency hides under this row's
    // scan/select/gather work.
    auto process = [&](v4f (&cur)[8], v4f (&nxt)[8], int r) {
        const int row = row0 + r;
        if (r + 1 < RPB) {
            const v4f* pn =
                reinterpret_cast<const v4f*>(A + (size_t)(row + 1) * NDIM);
            #pragma unroll
            for (int i = 0; i < 8; ++i)
                nxt[i] = __builtin_nontemporal_load(pn + i * 256 + tid);
        }
        const float xres = X[(size_t)row * DDIM + tid];

        // ---- Phase 1: threshold scan of register-resident row ---------
        // thr=2.45: count ~ Bin(8192,0.00714): E=58, sigma=7.6.
        // Retries (P~2e-4) re-scan registers — free. cand[] fill order is
        // racy; keys unique -> deterministic selection below.
        const float thrs[6] = {2.45f, 2.0f, 3.2f, 1.2f, 0.0f, -2.0f};
        bool ok = false;
        int count = 0;

        for (int ti = 0; ti < 6 && !ok; ++ti) {
            const float thr = thrs[ti];
            if (tid == 0) s_count = 0;
            __syncthreads();

            #pragma unroll
            for (int i = 0; i < 8; ++i) {
                const int base = (i * 256 + tid) * 4;
                #pragma unroll
                for (int c = 0; c < 4; ++c) {
                    const float f = cur[i][c];
                    if (f > thr) {
                        const int pos = atomicAdd(&s_count, 1);
                        if (pos < CAP) {
                            const int idx = base + c;
                            cand[pos] =
                                ((unsigned long long)f2key(f) << 32) |
                                (uint32_t)(~(uint32_t)idx);
                        }
                    }
                }
            }
            __syncthreads();
            count = s_count;           // uniform across block
            ok = (count >= k && count <= CAP);
            __syncthreads();           // protect s_count reset next iter
        }

        // ---- Phase 2: rank-based top-k selection (no sort) ------------
        if (ok) {
            // rank(i)=#{j: key_j>key_i}; unique keys -> unique ranks ->
            // race-free deterministic s_sel. 8x unroll = 8 LDS broadcast
            // reads in flight.
            if (tid < count) {
                const unsigned long long mykey = cand[tid];
                int rank = 0;
                int j = 0;
                for (; j + 8 <= count; j += 8) {
                    const unsigned long long c0 = cand[j + 0];
                    const unsigned long long c1 = cand[j + 1];
                    const unsigned long long c2 = cand[j + 2];
                    const unsigned long long c3 = cand[j + 3];
                    const unsigned long long c4 = cand[j + 4];
                    const unsigned long long c5 = cand[j + 5];
                    const unsigned long long c6 = cand[j + 6];
                    const unsigned long long c7 = cand[j + 7];
                    rank += (c0 > mykey) + (c1 > mykey) + (c2 > mykey) +
                            (c3 > mykey) + (c4 > mykey) + (c5 > mykey) +
                            (c6 > mykey) + (c7 > mykey);
                }
                for (; j < count; ++j)
                    rank += (cand[j] > mykey) ? 1 : 0;
                if (rank < k)
                    s_sel[rank] =
                        (int)(~(uint32_t)(mykey & 0xFFFFFFFFull));
            }
            __syncthreads();
        } else {
            // exact (slow) fallback — never triggers for normal data
            const float* __restrict__ rowp = A + (size_t)row * NDIM;
            for (int t = 0; t < k; ++t) {
                unsigned long long best = 0ull;
                for (int it = 0; it < NDIM / 256; ++it) {
                    const int idx = it * 256 + tid;
                    const float f = rowp[idx];
                    bool taken = false;
                    for (int s = 0; s < t; ++s) taken |= (s_sel[s] == idx);
                    if (!taken) {
                        const unsigned long long comp =
                            ((unsigned long long)f2key(f) << 32) |
                            (uint32_t)(~(uint32_t)idx);
                        if (comp > best) best = comp;
                    }
                }
                #pragma unroll
                for (int o = 32; o > 0; o >>= 1) {
                    const unsigned long long other =
                        __shfl_down(best, o, 64);
                    if (other > best) best = other;
                }
                if (lane == 0) s_red[wid] = best;
                __syncthreads();
                if (tid == 0) {
                    unsigned long long b = s_red[0];
                    for (int w = 1; w < 4; ++w)
                        if (s_red[w] > b) b = s_red[w];
                    s_sel[t] = (int)(~(uint32_t)(b & 0xFFFFFFFFull));
                }
                __syncthreads();
            }
        }

        // ---- Phase 3: gather + residual -------------------------------
        // tid == column d; wave reads of X rows are 256B contiguous,
        // L2/L3-hot (A uses nt loads so X stays resident). 8 accumulators
        // -> dependent chain ~4 L2 latencies, and it all overlaps the
        // next row's in-flight HBM loads.
        float acc;
        if (k == 32) {
            float a[8];
            #pragma unroll
            for (int q = 0; q < 8; ++q) a[q] = 0.f;
            #pragma unroll
            for (int t = 0; t < 32; ++t)
                a[t & 7] += X[(size_t)s_sel[t] * DDIM + tid];
            acc = ((a[0] + a[1]) + (a[2] + a[3])) +
                  ((a[4] + a[5]) + (a[6] + a[7]));
        } else {
            acc = 0.f;
            for (int t = 0; t < k; ++t)
                acc += X[(size_t)s_sel[t] * DDIM + tid];
        }
        __builtin_nontemporal_store(xres + alpha * acc,
                                    out + (size_t)row * DDIM + tid);
        // No barrier needed here: next row's phase-1 writes cand/s_count
        // (not s_sel) and its own barriers order them; s_sel is next
        // written only after two more barriers.
    };

    process(bufA, bufB, 0);
    process(bufB, bufA, 1);
    process(bufA, bufB, 2);
    process(bufB, bufA, 3);
}

extern "C" void kernel_launch(void* const* d_in, const int* in_sizes, int n_in,
                              void* d_out, int out_size, void* d_ws, size_t ws_size,
                              hipStream_t stream) {
    const float* A     = (const float*)d_in[0];
    const float* X     = (const float*)d_in[1];
    const float* alpha = (const float*)d_in[2];
    const int*   k     = (const int*)d_in[3];
    float* out = (float*)d_out;

    topk_agg_kernel<<<NDIM / RPB, 256, 0, stream>>>(A, X, alpha, k, out);
}

// Round 8
// 70.864 us; speedup vs baseline: 1.8118x; 1.8118x over previous
//
#include <hip/hip_runtime.h>
#include <stdint.h>

#define NDIM 8192
#define DDIM 256
#define CAP  256    // candidate capacity — LDS ~2.6 KB
#define MAXK 64     // sel stride in workspace

typedef float v4f __attribute__((ext_vector_type(4)));

// Map float bits to an unsigned key with the same total order.
__device__ inline uint32_t f2key(float f) {
    uint32_t u = __float_as_uint(f);
    return (u & 0x80000000u) ? ~u : (u | 0x80000000u);
}

// ---------------------------------------------------------------------------
// Kernel 1: stream a row of A, select top-k indices, write them to ws.
// No gather tail: the only post-scan work is the rank loop + k int writes.
// ---------------------------------------------------------------------------
__global__ __launch_bounds__(256) void scan_select_kernel(
    const float* __restrict__ A, const int* __restrict__ k_p,
    int* __restrict__ sel_ws)
{
    const int row  = blockIdx.x;
    const int tid  = threadIdx.x;
    const int lane = tid & 63;
    const int wid  = tid >> 6;

    __shared__ unsigned long long cand[CAP];
    __shared__ int s_count;
    __shared__ int s_sel[MAXK];
    __shared__ unsigned long long s_red[4];

    int k = *k_p;
    if (k > MAXK) k = MAXK;

    const float* __restrict__ rowp = A + (size_t)row * NDIM;

    // Register-resident row: 8 independent NT float4 loads (R4-proven).
    v4f v0, v1, v2, v3, v4, v5, v6, v7;
    {
        const v4f* p = reinterpret_cast<const v4f*>(rowp);
        v0 = __builtin_nontemporal_load(p + 0 * 256 + tid);
        v1 = __builtin_nontemporal_load(p + 1 * 256 + tid);
        v2 = __builtin_nontemporal_load(p + 2 * 256 + tid);
        v3 = __builtin_nontemporal_load(p + 3 * 256 + tid);
        v4 = __builtin_nontemporal_load(p + 4 * 256 + tid);
        v5 = __builtin_nontemporal_load(p + 5 * 256 + tid);
        v6 = __builtin_nontemporal_load(p + 6 * 256 + tid);
        v7 = __builtin_nontemporal_load(p + 7 * 256 + tid);
    }

    // Phase 1: threshold scan. thr=2.45: count ~ Bin(8192,0.00714),
    // E=58, sigma=7.6; retries are register re-scans.
    const float thrs[6] = {2.45f, 2.0f, 3.2f, 1.2f, 0.0f, -2.0f};
    bool ok = false;
    int count = 0;

    for (int ti = 0; ti < 6 && !ok; ++ti) {
        const float thr = thrs[ti];
        if (tid == 0) s_count = 0;
        __syncthreads();

        #pragma unroll
        for (int i = 0; i < 8; ++i) {
            const v4f v = (i == 0) ? v0 : (i == 1) ? v1 : (i == 2) ? v2 :
                          (i == 3) ? v3 : (i == 4) ? v4 : (i == 5) ? v5 :
                          (i == 6) ? v6 : v7;
            const int base = (i * 256 + tid) * 4;
            #pragma unroll
            for (int c = 0; c < 4; ++c) {
                const float f = v[c];
                if (f > thr) {
                    const int pos = atomicAdd(&s_count, 1);
                    if (pos < CAP) {
                        const int idx = base + c;
                        cand[pos] = ((unsigned long long)f2key(f) << 32) |
                                    (uint32_t)(~(uint32_t)idx);
                    }
                }
            }
        }
        __syncthreads();
        count = s_count;               // uniform across block
        ok = (count >= k && count <= CAP);
        __syncthreads();               // protect s_count reset next iter
    }

    // Phase 2: rank-based selection; winners go straight to global ws.
    if (ok) {
        if (tid < count) {
            const unsigned long long mykey = cand[tid];
            int rank = 0;
            int j = 0;
            for (; j + 8 <= count; j += 8) {
                const unsigned long long c0 = cand[j + 0];
                const unsigned long long c1 = cand[j + 1];
                const unsigned long long c2 = cand[j + 2];
                const unsigned long long c3 = cand[j + 3];
                const unsigned long long c4 = cand[j + 4];
                const unsigned long long c5 = cand[j + 5];
                const unsigned long long c6 = cand[j + 6];
                const unsigned long long c7 = cand[j + 7];
                rank += (c0 > mykey) + (c1 > mykey) + (c2 > mykey) +
                        (c3 > mykey) + (c4 > mykey) + (c5 > mykey) +
                        (c6 > mykey) + (c7 > mykey);
            }
            for (; j < count; ++j)
                rank += (cand[j] > mykey) ? 1 : 0;
            if (rank < k)
                sel_ws[(size_t)row * MAXK + rank] =
                    (int)(~(uint32_t)(mykey & 0xFFFFFFFFull));
        }
    } else {
        // exact (slow) fallback — never triggers for normal data
        for (int t = 0; t < k; ++t) {
            unsigned long long best = 0ull;
            for (int it = 0; it < NDIM / 256; ++it) {
                const int idx = it * 256 + tid;
                const float f = rowp[idx];
                bool taken = false;
                for (int s = 0; s < t; ++s) taken |= (s_sel[s] == idx);
                if (!taken) {
                    const unsigned long long comp =
                        ((unsigned long long)f2key(f) << 32) |
                        (uint32_t)(~(uint32_t)idx);
                    if (comp > best) best = comp;
                }
            }
            #pragma unroll
            for (int o = 32; o > 0; o >>= 1) {
                const unsigned long long other = __shfl_down(best, o, 64);
                if (other > best) best = other;
            }
            if (lane == 0) s_red[wid] = best;
            __syncthreads();
            if (tid == 0) {
                unsigned long long b = s_red[0];
                for (int w = 1; w < 4; ++w)
                    if (s_red[w] > b) b = s_red[w];
                s_sel[t] = (int)(~(uint32_t)(b & 0xFFFFFFFFull));
            }
            __syncthreads();
        }
        if (tid < k)
            sel_ws[(size_t)row * MAXK + tid] = s_sel[tid];
    }
}

// ---------------------------------------------------------------------------
// Kernel 2: gather + residual. X is L2/L3-hot; massive TLP hides latency.
// ---------------------------------------------------------------------------
__global__ __launch_bounds__(256) void gather_kernel(
    const float* __restrict__ X, const int* __restrict__ sel_ws,
    const float* __restrict__ alpha_p, const int* __restrict__ k_p,
    float* __restrict__ out)
{
    const int row = blockIdx.x;
    const int tid = threadIdx.x;

    __shared__ int s_sel[MAXK];

    int k = *k_p;
    if (k > MAXK) k = MAXK;
    const float alpha = *alpha_p;

    if (tid < k) s_sel[tid] = sel_ws[(size_t)row * MAXK + tid];
    const float xres = X[(size_t)row * DDIM + tid];
    __syncthreads();

    float acc;
    if (k == 32) {
        float a[8];
        #pragma unroll
        for (int q = 0; q < 8; ++q) a[q] = 0.f;
        #pragma unroll
        for (int t = 0; t < 32; ++t)
            a[t & 7] += X[(size_t)s_sel[t] * DDIM + tid];
        acc = ((a[0] + a[1]) + (a[2] + a[3])) +
              ((a[4] + a[5]) + (a[6] + a[7]));
    } else {
        acc = 0.f;
        for (int t = 0; t < k; ++t)
            acc += X[(size_t)s_sel[t] * DDIM + tid];
    }
    __builtin_nontemporal_store(xres + alpha * acc,
                                out + (size_t)row * DDIM + tid);
}

// ---------------------------------------------------------------------------
// Fused fallback (R5 structure, 68 us proven) — used only if ws is too small.
// ---------------------------------------------------------------------------
__global__ __launch_bounds__(256) void topk_agg_fused(
    const float* __restrict__ A, const float* __restrict__ X,
    const float* __restrict__ alpha_p, const int* __restrict__ k_p,
    float* __restrict__ out)
{
    const int row  = blockIdx.x;
    const int tid  = threadIdx.x;
    const int lane = tid & 63;
    const int wid  = tid >> 6;

    __shared__ unsigned long long cand[CAP];
    __shared__ int s_count;
    __shared__ int s_sel[MAXK];
    __shared__ unsigned long long s_red[4];

    int k = *k_p;
    if (k > MAXK) k = MAXK;
    const float alpha = *alpha_p;

    const float* __restrict__ rowp = A + (size_t)row * NDIM;
    const float xres = X[(size_t)row * DDIM + tid];

    v4f v0, v1, v2, v3, v4, v5, v6, v7;
    {
        const v4f* p = reinterpret_cast<const v4f*>(rowp);
        v0 = __builtin_nontemporal_load(p + 0 * 256 + tid);
        v1 = __builtin_nontemporal_load(p + 1 * 256 + tid);
        v2 = __builtin_nontemporal_load(p + 2 * 256 + tid);
        v3 = __builtin_nontemporal_load(p + 3 * 256 + tid);
        v4 = __builtin_nontemporal_load(p + 4 * 256 + tid);
        v5 = __builtin_nontemporal_load(p + 5 * 256 + tid);
        v6 = __builtin_nontemporal_load(p + 6 * 256 + tid);
        v7 = __builtin_nontemporal_load(p + 7 * 256 + tid);
    }

    const float thrs[6] = {2.45f, 2.0f, 3.2f, 1.2f, 0.0f, -2.0f};
    bool ok = false;
    int count = 0;

    for (int ti = 0; ti < 6 && !ok; ++ti) {
        const float thr = thrs[ti];
        if (tid == 0) s_count = 0;
        __syncthreads();
        #pragma unroll
        for (int i = 0; i < 8; ++i) {
            const v4f v = (i == 0) ? v0 : (i == 1) ? v1 : (i == 2) ? v2 :
                          (i == 3) ? v3 : (i == 4) ? v4 : (i == 5) ? v5 :
                          (i == 6) ? v6 : v7;
            const int base = (i * 256 + tid) * 4;
            #pragma unroll
            for (int c = 0; c < 4; ++c) {
                const float f = v[c];
                if (f > thr) {
                    const int pos = atomicAdd(&s_count, 1);
                    if (pos < CAP) {
                        const int idx = base + c;
                        cand[pos] = ((unsigned long long)f2key(f) << 32) |
                                    (uint32_t)(~(uint32_t)idx);
                    }
                }
            }
        }
        __syncthreads();
        count = s_count;
        ok = (count >= k && count <= CAP);
        __syncthreads();
    }

    if (ok) {
        if (tid < count) {
            const unsigned long long mykey = cand[tid];
            int rank = 0;
            int j = 0;
            for (; j + 8 <= count; j += 8) {
                const unsigned long long c0 = cand[j + 0];
                const unsigned long long c1 = cand[j + 1];
                const unsigned long long c2 = cand[j + 2];
                const unsigned long long c3 = cand[j + 3];
                const unsigned long long c4 = cand[j + 4];
                const unsigned long long c5 = cand[j + 5];
                const unsigned long long c6 = cand[j + 6];
                const unsigned long long c7 = cand[j + 7];
                rank += (c0 > mykey) + (c1 > mykey) + (c2 > mykey) +
                        (c3 > mykey) + (c4 > mykey) + (c5 > mykey) +
                        (c6 > mykey) + (c7 > mykey);
            }
            for (; j < count; ++j)
                rank += (cand[j] > mykey) ? 1 : 0;
            if (rank < k)
                s_sel[rank] = (int)(~(uint32_t)(mykey & 0xFFFFFFFFull));
        }
        __syncthreads();
    } else {
        for (int t = 0; t < k; ++t) {
            unsigned long long best = 0ull;
            for (int it = 0; it < NDIM / 256; ++it) {
                const int idx = it * 256 + tid;
                const float f = rowp[idx];
                bool taken = false;
                for (int s = 0; s < t; ++s) taken |= (s_sel[s] == idx);
                if (!taken) {
                    const unsigned long long comp =
                        ((unsigned long long)f2key(f) << 32) |
                        (uint32_t)(~(uint32_t)idx);
                    if (comp > best) best = comp;
                }
            }
            #pragma unroll
            for (int o = 32; o > 0; o >>= 1) {
                const unsigned long long other = __shfl_down(best, o, 64);
                if (other > best) best = other;
            }
            if (lane == 0) s_red[wid] = best;
            __syncthreads();
            if (tid == 0) {
                unsigned long long b = s_red[0];
                for (int w = 1; w < 4; ++w)
                    if (s_red[w] > b) b = s_red[w];
                s_sel[t] = (int)(~(uint32_t)(b & 0xFFFFFFFFull));
            }
            __syncthreads();
        }
    }

    float acc;
    if (k == 32) {
        float a[8];
        #pragma unroll
        for (int q = 0; q < 8; ++q) a[q] = 0.f;
        #pragma unroll
        for (int t = 0; t < 32; ++t)
            a[t & 7] += X[(size_t)s_sel[t] * DDIM + tid];
        acc = ((a[0] + a[1]) + (a[2] + a[3])) +
              ((a[4] + a[5]) + (a[6] + a[7]));
    } else {
        acc = 0.f;
        for (int t = 0; t < k; ++t)
            acc += X[(size_t)s_sel[t] * DDIM + tid];
    }
    __builtin_nontemporal_store(xres + alpha * acc,
                                out + (size_t)row * DDIM + tid);
}

extern "C" void kernel_launch(void* const* d_in, const int* in_sizes, int n_in,
                              void* d_out, int out_size, void* d_ws, size_t ws_size,
                              hipStream_t stream) {
    const float* A     = (const float*)d_in[0];
    const float* X     = (const float*)d_in[1];
    const float* alpha = (const float*)d_in[2];
    const int*   k     = (const int*)d_in[3];
    float* out = (float*)d_out;

    const size_t sel_bytes = (size_t)NDIM * MAXK * sizeof(int);
    if (ws_size >= sel_bytes) {
        int* sel = (int*)d_ws;
        scan_select_kernel<<<NDIM, 256, 0, stream>>>(A, k, sel);
        gather_kernel<<<NDIM, 256, 0, stream>>>(X, sel, alpha, k, out);
    } else {
        topk_agg_fused<<<NDIM, 256, 0, stream>>>(A, X, alpha, k, out);
    }
}